// Round 4
// baseline (517.196 us; speedup 1.0000x reference)
//
#include <hip/hip_runtime.h>
#include <math.h>

// Qwen3 MoE gate: logits = hidden @ W_gate^T ; softmax ; top-8 ; renorm.
// Outputs (flat f32): sel_w [T*8], sel_idx-as-float [T*8], logits [T*64].
//
// R4: lane=token formulation. W_gate rows are wave-uniform -> s_load (scalar
// pipe, SGPR operand of v_fmac) — LDS pipe was the R3 bound (8 b128 reads
// per 128 FMA-cycles ~3x oversubscribed). H staged coalesced->LDS per-wave
// (no barriers in k-loop), 8-wave k-split for occupancy, LDS tree-reduce,
// wave 0 fuses top-9 scan + flag append. fp64 fixup for near-ties unchanged.

#define HDIM 2048
#define NEXP 64
#define TOPK 8
#define NSCAN 9
#define TAU  2.5e-4f

#define KSPLIT 8                 // waves per block = k-split factor
#define TOKB   64                // tokens per block (= lanes per wave)
#define KWIN   (HDIM / KSPLIT)   // 256 floats per wave
#define CHUNK  32                // floats staged per chunk
#define NCH    (KWIN / CHUNK)    // 8 chunks
#define ROWF   36                // padded floats per token row (16B-aligned, bank-balanced)
#define SLOTF  (TOKB * ROWF)     // 2304 floats per wave slot
#define REDROW 68                // reduction row pad (16B-aligned, bank-balanced)
#define REDSL  (TOKB * REDROW)   // 4352 floats per reduction slice

__global__ __launch_bounds__(512, 2) void gate_gemm_topk(
    const float* __restrict__ hidden,   // [T, 2048]
    const float* __restrict__ wgate,    // [64, 2048]
    float* __restrict__ logits,         // [T, 64]
    float* __restrict__ selw,           // [T, 8]
    float* __restrict__ selidx,         // [T, 8]
    int* __restrict__ cnt,
    int* __restrict__ list)
{
    __shared__ float lds[KSPLIT * SLOTF];   // 18432 floats = 72 KiB (>= 4*REDSL)

    const int tid  = threadIdx.x;
    const int lane = tid & 63;
    const int wv   = __builtin_amdgcn_readfirstlane(tid >> 6);  // scalar wave id
    const size_t tokBase = (size_t)blockIdx.x * TOKB;
    const int   kbase = wv * KWIN;          // scalar: this wave's k-window
    float* slot = &lds[wv * SLOTF];

    float acc[NEXP];
#pragma unroll
    for (int e = 0; e < NEXP; ++e) acc[e] = 0.f;

    // staging map: float4-flat f = p*64+lane; tok = f>>3 (0..63), c4 = f&7.
    // global: 8 tokens x 128B contiguous per instr (fully coalesced).
    const int stok = (lane >> 3);           // + p*8
    const int sc4  = (lane & 7);

    float4 sreg[8];
#pragma unroll
    for (int p = 0; p < 8; ++p)
        sreg[p] = *reinterpret_cast<const float4*>(
            &hidden[(tokBase + p * 8 + stok) * HDIM + kbase + sc4 * 4]);
#pragma unroll
    for (int p = 0; p < 8; ++p)
        *reinterpret_cast<float4*>(&slot[(p * 8 + stok) * ROWF + sc4 * 4]) = sreg[p];

    for (int c = 0; c < NCH; ++c) {
        // issue next chunk's global loads early (land during 2048 FMAs)
        if (c + 1 < NCH) {
#pragma unroll
            for (int p = 0; p < 8; ++p)
                sreg[p] = *reinterpret_cast<const float4*>(
                    &hidden[(tokBase + p * 8 + stok) * HDIM + kbase
                            + (c + 1) * CHUNK + sc4 * 4]);
        }
        // own token's 32 h-values from LDS (8 b128, bank-balanced)
        float4 hv[8];
#pragma unroll
        for (int q = 0; q < 8; ++q)
            hv[q] = *reinterpret_cast<const float4*>(&slot[lane * ROWF + q * 4]);

        // W: fully uniform address (kbase scalar, e/q compile-time) -> s_load,
        // consumed as the SGPR operand of v_fmac_f32.
        const float* wb = &wgate[kbase + c * CHUNK];
#pragma unroll
        for (int e = 0; e < NEXP; ++e) {
            const float* we = &wb[e * HDIM];
#pragma unroll
            for (int q = 0; q < 8; ++q) {
                const float4 w4 = *reinterpret_cast<const float4*>(&we[q * 4]);
                acc[e] += hv[q].x * w4.x;
                acc[e] += hv[q].y * w4.y;
                acc[e] += hv[q].z * w4.z;
                acc[e] += hv[q].w * w4.w;
            }
        }

        if (c + 1 < NCH) {
#pragma unroll
            for (int p = 0; p < 8; ++p)
                *reinterpret_cast<float4*>(
                    &slot[(p * 8 + stok) * ROWF + sc4 * 4]) = sreg[p];
        }
    }

    // ---- tree-reduce the 8 k-partials (reuse lds; slot data dead) ----
    __syncthreads();
    // round 1: waves 4..7 -> slices 0..3
    if (wv >= 4) {
        float* r = &lds[(wv - 4) * REDSL + lane * REDROW];
#pragma unroll
        for (int q = 0; q < 16; ++q)
            *reinterpret_cast<float4*>(&r[q * 4]) =
                make_float4(acc[4 * q], acc[4 * q + 1], acc[4 * q + 2], acc[4 * q + 3]);
    }
    __syncthreads();
    if (wv < 4) {
        const float* r = &lds[wv * REDSL + lane * REDROW];
#pragma unroll
        for (int q = 0; q < 16; ++q) {
            const float4 v = *reinterpret_cast<const float4*>(&r[q * 4]);
            acc[4 * q] += v.x; acc[4 * q + 1] += v.y;
            acc[4 * q + 2] += v.z; acc[4 * q + 3] += v.w;
        }
    }
    __syncthreads();
    // round 2: waves 2..3 -> slices 0..1
    if (wv >= 2 && wv < 4) {
        float* r = &lds[(wv - 2) * REDSL + lane * REDROW];
#pragma unroll
        for (int q = 0; q < 16; ++q)
            *reinterpret_cast<float4*>(&r[q * 4]) =
                make_float4(acc[4 * q], acc[4 * q + 1], acc[4 * q + 2], acc[4 * q + 3]);
    }
    __syncthreads();
    if (wv < 2) {
        const float* r = &lds[wv * REDSL + lane * REDROW];
#pragma unroll
        for (int q = 0; q < 16; ++q) {
            const float4 v = *reinterpret_cast<const float4*>(&r[q * 4]);
            acc[4 * q] += v.x; acc[4 * q + 1] += v.y;
            acc[4 * q + 2] += v.z; acc[4 * q + 3] += v.w;
        }
    }
    __syncthreads();
    // round 3: wave 1 -> slice 0
    if (wv == 1) {
        float* r = &lds[lane * REDROW];
#pragma unroll
        for (int q = 0; q < 16; ++q)
            *reinterpret_cast<float4*>(&r[q * 4]) =
                make_float4(acc[4 * q], acc[4 * q + 1], acc[4 * q + 2], acc[4 * q + 3]);
    }
    __syncthreads();

    if (wv == 0) {
        const float* r = &lds[lane * REDROW];
#pragma unroll
        for (int q = 0; q < 16; ++q) {
            const float4 v = *reinterpret_cast<const float4*>(&r[q * 4]);
            acc[4 * q] += v.x; acc[4 * q + 1] += v.y;
            acc[4 * q + 2] += v.z; acc[4 * q + 3] += v.w;
        }

        const size_t t = tokBase + lane;
        // logits out
#pragma unroll
        for (int q = 0; q < 16; ++q)
            *reinterpret_cast<float4*>(&logits[t * NEXP + q * 4]) =
                make_float4(acc[4 * q], acc[4 * q + 1], acc[4 * q + 2], acc[4 * q + 3]);

        // fused top-9 scan (static indexing; '>' ascending == lax.top_k tie-break)
        float bv[NSCAN];
        int   bidx[NSCAN];
        unsigned long long used = 0ull;
#pragma unroll
        for (int k = 0; k < NSCAN; ++k) {
            float best = -INFINITY;
            int   bi   = 0;
#pragma unroll
            for (int i = 0; i < NEXP; ++i) {
                const bool avail = ((used >> i) & 1ull) == 0ull;
                if (avail && acc[i] > best) { best = acc[i]; bi = i; }
            }
            bv[k]   = best;
            bidx[k] = bi;
            used |= (1ull << bi);
        }

        float ming = bv[0] - bv[1];
#pragma unroll
        for (int k = 1; k < NSCAN - 1; ++k) ming = fminf(ming, bv[k] - bv[k + 1]);
        if (ming < TAU) {
            const int pos = atomicAdd(cnt, 1);   // order-free: fixup is per-token
            list[pos] = (int)t;
        }

        const float m = bv[0];
        float ek[TOPK];
        float s = 0.f;
#pragma unroll
        for (int k = 0; k < TOPK; ++k) { ek[k] = expf(bv[k] - m); s += ek[k]; }
        const float inv = 1.0f / s;
#pragma unroll
        for (int k = 0; k < TOPK; ++k) {
            selw[t * TOPK + k]   = ek[k] * inv;
            selidx[t * TOPK + k] = (float)bidx[k];
        }
    }
}

// ---------------- fp64 re-dot + exact top-8 for flagged tokens ------------
__global__ __launch_bounds__(256) void gate_fixup_f64(
    const float* __restrict__ hidden,
    const float* __restrict__ wgate,
    const int* __restrict__ cnt,
    const int* __restrict__ list,
    float* __restrict__ selw,
    float* __restrict__ selidx)
{
    const int lane   = threadIdx.x & 63;
    const int waveId = (blockIdx.x * blockDim.x + threadIdx.x) >> 6;
    const int nWaves = (gridDim.x * blockDim.x) >> 6;
    const int n      = *cnt;

    for (int i = waveId; i < n; i += nWaves) {
        const int t = list[i];
        const float* hrow = &hidden[(size_t)t * HDIM];
        const float* wrow = &wgate[(size_t)lane * HDIM];

        double a0 = 0.0, a1 = 0.0, a2 = 0.0, a3 = 0.0;
#pragma unroll 2
        for (int k = 0; k < HDIM; k += 16) {
            const float4 h0 = *reinterpret_cast<const float4*>(&hrow[k +  0]);
            const float4 h1 = *reinterpret_cast<const float4*>(&hrow[k +  4]);
            const float4 h2 = *reinterpret_cast<const float4*>(&hrow[k +  8]);
            const float4 h3 = *reinterpret_cast<const float4*>(&hrow[k + 12]);
            const float4 w0 = *reinterpret_cast<const float4*>(&wrow[k +  0]);
            const float4 w1 = *reinterpret_cast<const float4*>(&wrow[k +  4]);
            const float4 w2 = *reinterpret_cast<const float4*>(&wrow[k +  8]);
            const float4 w3 = *reinterpret_cast<const float4*>(&wrow[k + 12]);
            a0 += (double)h0.x * w0.x + (double)h0.y * w0.y
                + (double)h0.z * w0.z + (double)h0.w * w0.w;
            a1 += (double)h1.x * w1.x + (double)h1.y * w1.y
                + (double)h1.z * w1.z + (double)h1.w * w1.w;
            a2 += (double)h2.x * w2.x + (double)h2.y * w2.y
                + (double)h2.z * w2.z + (double)h2.w * w2.w;
            a3 += (double)h3.x * w3.x + (double)h3.y * w3.y
                + (double)h3.z * w3.z + (double)h3.w * w3.w;
        }
        double v = (a0 + a1) + (a2 + a3);
        int   id = lane;

        double bv[TOPK];
        int    bidx[TOPK];
#pragma unroll
        for (int p = 0; p < TOPK; ++p) {
            double mv = v;
            int    mi = id;
#pragma unroll
            for (int off = 32; off >= 1; off >>= 1) {
                const double ov = __shfl_xor(mv, off);
                const int    oi = __shfl_xor(mi, off);
                if (ov > mv || (ov == mv && oi < mi)) { mv = ov; mi = oi; }
            }
            bv[p]   = mv;
            bidx[p] = mi;
            if (id == mi) v = -INFINITY;
        }

        if (lane == 0) {
            float ek[TOPK];
            float s = 0.f;
#pragma unroll
            for (int p = 0; p < TOPK; ++p) {
                ek[p] = expf((float)(bv[p] - bv[0]));
                s += ek[p];
            }
            const float inv = 1.0f / s;
#pragma unroll
            for (int p = 0; p < TOPK; ++p) {
                selw[(size_t)t * TOPK + p]   = ek[p] * inv;
                selidx[(size_t)t * TOPK + p] = (float)bidx[p];
            }
        }
    }
}

extern "C" void kernel_launch(void* const* d_in, const int* in_sizes, int n_in,
                              void* d_out, int out_size, void* d_ws, size_t ws_size,
                              hipStream_t stream) {
    const float* hidden = (const float*)d_in[0];   // [4,4096,2048] f32
    const float* wgate  = (const float*)d_in[1];   // [64,2048] f32

    const int T = in_sizes[0] / HDIM;              // 16384 tokens

    float* out    = (float*)d_out;
    float* selw   = out;                           // T*8
    float* selidx = out + (size_t)T * TOPK;        // T*8
    float* logits = out + (size_t)2 * T * TOPK;    // T*64

    int* cnt  = (int*)d_ws;
    int* list = (int*)d_ws + 64;

    hipMemsetAsync(d_ws, 0, 256, stream);

    gate_gemm_topk<<<T / TOKB, 512, 0, stream>>>(hidden, wgate, logits,
                                                 selw, selidx, cnt, list);
    gate_fixup_f64<<<256, 256, 0, stream>>>(hidden, wgate, cnt, list, selw, selidx);
}